// Round 2
// baseline (341.702 us; speedup 1.0000x reference)
//
#include <hip/hip_runtime.h>

#define NN 200000   // nodes; D=128 features, 40 classes (padded to 48 in wt)

typedef __attribute__((ext_vector_type(8))) short bf16x8;
typedef __attribute__((ext_vector_type(4))) float f32x4;
typedef __attribute__((ext_vector_type(4))) unsigned int u32x4;

// round-to-nearest-even fp32 -> bf16 bits (prep kernel only)
static __device__ __forceinline__ short f2bf(float f) {
    unsigned u = __builtin_bit_cast(unsigned, f);
    u += 0x7fffu + ((u >> 16) & 1u);
    return (short)(u >> 16);
}

// pack 2 floats -> 2 bf16 in one u32 (round-half-up: add 0x8000, take hi16)
// result: hi16(b) in upper short, hi16(a) in lower short  (element order lo=a)
static __device__ __forceinline__ unsigned pk2(float a, float b) {
    unsigned ua = __builtin_bit_cast(unsigned, a) + 0x8000u;
    unsigned ub = __builtin_bit_cast(unsigned, b) + 0x8000u;
    return __builtin_amdgcn_perm(ub, ua, 0x07060302u);
}

// XOR-swizzled LDS offset for element (r, k) of a [*,128] bf16 tile.
// 8-elem (16B) chunks xored with (r&15) -> conflict-free ds_read_b128.
static __device__ __forceinline__ int swz(int r, int k) {
    return (r << 7) + (((k >> 3) ^ (r & 15)) << 3) + (k & 7);
}

// Pre-transpose + bf16-convert weights into workspace (elements):
// [0) Wt0[n][k]=W0[k][n] 128x128 | [16384) Wt1 | [32768) Wt2 | [49152) Wt3 48x128 (n>=40 zero)
__global__ void prep_weights_k(const float* __restrict__ W0, const float* __restrict__ W1,
                               const float* __restrict__ W2, const float* __restrict__ W3,
                               short* __restrict__ wt) {
    int e = blockIdx.x * 256 + threadIdx.x;   // 216 blocks * 256 = 55296
    if (e < 49152) {
        int l = e >> 14;
        int i = e & 16383;
        int n = i >> 7, k = i & 127;
        const float* W = (l == 0) ? W0 : ((l == 1) ? W1 : W2);
        wt[e] = f2bf(W[(k << 7) + n]);
    } else if (e < 55296) {
        int i = e - 49152;
        int n = i >> 7, k = i & 127;
        wt[e] = (n < 40) ? f2bf(W3[k * 40 + n]) : (short)0;
    }
}

// Fully fused 4-layer MLP + log_softmax. ZERO __syncthreads:
//  - activations live in a per-wave-private 8KB LDS slice (32 rows x 128 bf16)
//  - weight B-fragments are loaded straight from global wt (L1/L2-hot, 108KB total)
// 32KB LDS/block; __launch_bounds__(256,4) caps VGPR<=128 -> 16 waves/CU.
__global__ __launch_bounds__(256, 4)
void mlp_fused_k(const float* __restrict__ x, const short* __restrict__ wt,
                 const float* __restrict__ b0, const float* __restrict__ b1,
                 const float* __restrict__ b2, const float* __restrict__ b3,
                 float* __restrict__ out) {
    __shared__ __align__(16) short sA[4][32 * 128];   // 32 KB total

    const int tid  = (int)threadIdx.x;
    const int lane = tid & 63;
    const int wv   = tid >> 6;       // wave 0..3
    const int m    = lane & 15;      // row (A) / col (B,C) within 16-tile
    const int quad = lane >> 4;      // 0..3
    short* sAw = &sA[wv][0];         // this wave's private activation slice
    const int grow0 = (int)blockIdx.x * 128 + wv * 32;   // first global row

    // per-lane weight fragment base: row (ct*16+m), k (ks*32+quad*8)
    const short* wb = wt + m * 128 + quad * 8;

    f32x4 acc[2][8];
    auto zacc = [&]() {
        #pragma unroll
        for (int rt = 0; rt < 2; ++rt)
            #pragma unroll
            for (int ct = 0; ct < 8; ++ct)
                #pragma unroll
                for (int r = 0; r < 4; ++r) acc[rt][ct][r] = 0.f;
    };

    // bias + SiLU + bf16 -> sAw (wave-private rows 0..31), no barrier needed
    auto epilogue = [&](const float* __restrict__ bias) {
        float bv[8];
        #pragma unroll
        for (int ct = 0; ct < 8; ++ct) bv[ct] = bias[(ct << 4) + m];
        #pragma unroll
        for (int rt = 0; rt < 2; ++rt)
            #pragma unroll
            for (int ct = 0; ct < 8; ++ct)
                #pragma unroll
                for (int r = 0; r < 4; ++r) {
                    float v = acc[rt][ct][r] + bv[ct];
                    float h = v * __builtin_amdgcn_rcpf(1.f + __expf(-v));
                    int rl = (rt << 4) + (quad << 2) + r;    // C/D: row = quad*4+reg
                    unsigned u = __builtin_bit_cast(unsigned, h) + 0x8000u;
                    sAw[swz(rl, (ct << 4) + m)] = (short)(u >> 16);
                }
    };

    // dense layer with A from the wave-private LDS slice, B from global
    auto dense = [&](int lbase) {
        zacc();
        #pragma unroll
        for (int ks = 0; ks < 4; ++ks) {
            int kk = (ks << 5) + (quad << 3);
            bf16x8 a0 = *(const bf16x8*)&sAw[swz(m, kk)];
            bf16x8 a1 = *(const bf16x8*)&sAw[swz(16 + m, kk)];
            const short* wk = wb + lbase + (ks << 5);
            #pragma unroll
            for (int ct = 0; ct < 8; ++ct) {
                bf16x8 b = *(const bf16x8*)(wk + (ct << 11));
                acc[0][ct] = __builtin_amdgcn_mfma_f32_16x16x32_bf16(a0, b, acc[0][ct], 0, 0, 0);
                acc[1][ct] = __builtin_amdgcn_mfma_f32_16x16x32_bf16(a1, b, acc[1][ct], 0, 0, 0);
            }
        }
    };

    // ---------------- layer 0: A straight from global x (NT, packed cvt) ----
    zacc();
    {
        int g0 = grow0 + m, g1 = g0 + 16;
        long r0 = (g0 < NN) ? g0 : (NN - 1);
        long r1 = (g1 < NN) ? g1 : (NN - 1);
        const f32x4* p0 = (const f32x4*)(x + (r0 << 7)) + quad * 2;
        const f32x4* p1 = (const f32x4*)(x + (r1 << 7)) + quad * 2;
        #pragma unroll
        for (int ks = 0; ks < 4; ++ks) {
            f32x4 v0a = __builtin_nontemporal_load(p0 + ks * 8);
            f32x4 v0b = __builtin_nontemporal_load(p0 + ks * 8 + 1);
            f32x4 v1a = __builtin_nontemporal_load(p1 + ks * 8);
            f32x4 v1b = __builtin_nontemporal_load(p1 + ks * 8 + 1);
            u32x4 ua0, ua1;
            ua0[0] = pk2(v0a[0], v0a[1]); ua0[1] = pk2(v0a[2], v0a[3]);
            ua0[2] = pk2(v0b[0], v0b[1]); ua0[3] = pk2(v0b[2], v0b[3]);
            ua1[0] = pk2(v1a[0], v1a[1]); ua1[1] = pk2(v1a[2], v1a[3]);
            ua1[2] = pk2(v1b[0], v1b[1]); ua1[3] = pk2(v1b[2], v1b[3]);
            bf16x8 a0 = __builtin_bit_cast(bf16x8, ua0);
            bf16x8 a1 = __builtin_bit_cast(bf16x8, ua1);
            const short* wk = wb + (ks << 5);
            #pragma unroll
            for (int ct = 0; ct < 8; ++ct) {
                bf16x8 b = *(const bf16x8*)(wk + (ct << 11));
                acc[0][ct] = __builtin_amdgcn_mfma_f32_16x16x32_bf16(a0, b, acc[0][ct], 0, 0, 0);
                acc[1][ct] = __builtin_amdgcn_mfma_f32_16x16x32_bf16(a1, b, acc[1][ct], 0, 0, 0);
            }
        }
    }
    epilogue(b0);

    // ---------------- layers 1, 2 ----------------
    dense(16384);
    epilogue(b1);
    dense(32768);
    epilogue(b2);

    // ---------------- layer 3 + log_softmax ----------------
    f32x4 c3[2][3];
    #pragma unroll
    for (int rt = 0; rt < 2; ++rt)
        #pragma unroll
        for (int ct = 0; ct < 3; ++ct)
            #pragma unroll
            for (int r = 0; r < 4; ++r) c3[rt][ct][r] = 0.f;
    #pragma unroll
    for (int ks = 0; ks < 4; ++ks) {
        int kk = (ks << 5) + (quad << 3);
        bf16x8 a0 = *(const bf16x8*)&sAw[swz(m, kk)];
        bf16x8 a1 = *(const bf16x8*)&sAw[swz(16 + m, kk)];
        const short* wk = wb + 49152 + (ks << 5);
        #pragma unroll
        for (int ct = 0; ct < 3; ++ct) {
            bf16x8 b = *(const bf16x8*)(wk + (ct << 11));
            c3[0][ct] = __builtin_amdgcn_mfma_f32_16x16x32_bf16(a0, b, c3[0][ct], 0, 0, 0);
            c3[1][ct] = __builtin_amdgcn_mfma_f32_16x16x32_bf16(a1, b, c3[1][ct], 0, 0, 0);
        }
    }
    const bool val2 = (m < 8);                    // cols 32..39 valid
    float bv0 = b3[m];
    float bv1 = b3[16 + m];
    float bv2 = val2 ? b3[32 + m] : 0.f;
    #pragma unroll
    for (int rt = 0; rt < 2; ++rt) {
        #pragma unroll
        for (int r = 0; r < 4; ++r) {
            float v0 = c3[rt][0][r] + bv0;
            float v1 = c3[rt][1][r] + bv1;
            float v2 = c3[rt][2][r] + bv2;
            // row lives on the 16 lanes of this quad-group; reduce cols 0..39
            float mx = fmaxf(v0, v1);
            mx = val2 ? fmaxf(mx, v2) : mx;
            #pragma unroll
            for (int s = 1; s < 16; s <<= 1)
                mx = fmaxf(mx, __shfl_xor(mx, s, 64));
            float sm = __expf(v0 - mx) + __expf(v1 - mx) + (val2 ? __expf(v2 - mx) : 0.f);
            #pragma unroll
            for (int s = 1; s < 16; s <<= 1)
                sm += __shfl_xor(sm, s, 64);
            float L = mx + __logf(sm);
            int grow = grow0 + (rt << 4) + (quad << 2) + r;
            if (grow < NN) {
                float* orow = out + (long)grow * 40;
                __builtin_nontemporal_store(v0 - L, orow + m);
                __builtin_nontemporal_store(v1 - L, orow + 16 + m);
                if (val2) __builtin_nontemporal_store(v2 - L, orow + 32 + m);
            }
        }
    }
}

extern "C" void kernel_launch(void* const* d_in, const int* in_sizes, int n_in,
                              void* d_out, int out_size, void* d_ws, size_t ws_size,
                              hipStream_t stream) {
    const float* x   = (const float*)d_in[0];
    // d_in[1] = edge_index (unused: ChebConv K=1 ignores the Laplacian)
    const float* W0  = (const float*)d_in[2];
    const float* bb0 = (const float*)d_in[3];
    const float* W1  = (const float*)d_in[4];
    const float* bb1 = (const float*)d_in[5];
    const float* W2  = (const float*)d_in[6];
    const float* bb2 = (const float*)d_in[7];
    const float* W3  = (const float*)d_in[8];
    const float* bb3 = (const float*)d_in[9];
    short* wt  = (short*)d_ws;         // 110592 B of bf16 transposed weights
    float* out = (float*)d_out;

    hipLaunchKernelGGL(prep_weights_k, dim3(216), dim3(256), 0, stream, W0, W1, W2, W3, wt);
    hipLaunchKernelGGL(mlp_fused_k, dim3((NN + 127) / 128), dim3(256), 0, stream,
                       x, wt, bb0, bb1, bb2, bb3, out);
}

// Round 3
// 332.514 us; speedup vs baseline: 1.0276x; 1.0276x over previous
//
#include <hip/hip_runtime.h>

#define NN 200000   // nodes; D=128 features, 40 classes (padded to 48 in wt)

typedef __attribute__((ext_vector_type(8))) short bf16x8;
typedef __attribute__((ext_vector_type(4))) float f32x4;
typedef __attribute__((ext_vector_type(4))) unsigned int u32x4;

// round-to-nearest-even fp32 -> bf16 bits (prep kernel only)
static __device__ __forceinline__ short f2bf(float f) {
    unsigned u = __builtin_bit_cast(unsigned, f);
    u += 0x7fffu + ((u >> 16) & 1u);
    return (short)(u >> 16);
}

// pack 2 floats -> 2 bf16 in one u32 (round-half-up: add 0x8000, take hi16)
static __device__ __forceinline__ unsigned pk2(float a, float b) {
    unsigned ua = __builtin_bit_cast(unsigned, a) + 0x8000u;
    unsigned ub = __builtin_bit_cast(unsigned, b) + 0x8000u;
    return __builtin_amdgcn_perm(ub, ua, 0x07060302u);
}

// XOR-swizzled LDS offset for element (r, k) of a [*,128] bf16 tile.
// 8-elem (16B) chunks xored with (r&15) -> conflict-free ds_read_b128.
static __device__ __forceinline__ int swz(int r, int k) {
    return (r << 7) + (((k >> 3) ^ (r & 15)) << 3) + (k & 7);
}

// Pre-transpose + bf16-convert weights into workspace (elements):
// [0) Wt0[n][k]=W0[k][n] 128x128 | [16384) Wt1 | [32768) Wt2 | [49152) Wt3 48x128 (n>=40 zero)
__global__ void prep_weights_k(const float* __restrict__ W0, const float* __restrict__ W1,
                               const float* __restrict__ W2, const float* __restrict__ W3,
                               short* __restrict__ wt) {
    int e = blockIdx.x * 256 + threadIdx.x;   // 216 blocks * 256 = 55296
    if (e < 49152) {
        int l = e >> 14;
        int i = e & 16383;
        int n = i >> 7, k = i & 127;
        const float* W = (l == 0) ? W0 : ((l == 1) ? W1 : W2);
        wt[e] = f2bf(W[(k << 7) + n]);
    } else if (e < 55296) {
        int i = e - 49152;
        int n = i >> 7, k = i & 127;
        wt[e] = (n < 40) ? f2bf(W3[k * 40 + n]) : (short)0;
    }
}

// Fully fused 4-layer MLP + log_softmax. ZERO __syncthreads:
//  - activations live in a per-wave-private 8KB LDS slice (32 rows x 128 bf16)
//  - weight B-fragments are loaded straight from global wt (L1/L2-hot, 108KB total)
// 32KB LDS/block; (256,4): 64 arch VGPR + 64 AGPR acc = 128 -> 4 waves/SIMD.
__global__ __launch_bounds__(256, 4)
void mlp_fused_k(const float* __restrict__ x, const short* __restrict__ wt,
                 const float* __restrict__ b0, const float* __restrict__ b1,
                 const float* __restrict__ b2, const float* __restrict__ b3,
                 float* __restrict__ out) {
    __shared__ __align__(16) short sA[4][32 * 128];   // 32 KB total

    const int tid  = (int)threadIdx.x;
    const int lane = tid & 63;
    const int wv   = tid >> 6;       // wave 0..3
    const int m    = lane & 15;      // row (A) / col (B,C) within 16-tile
    const int quad = lane >> 4;      // 0..3
    short* sAw = &sA[wv][0];         // this wave's private activation slice
    const int grow0 = (int)blockIdx.x * 128 + wv * 32;   // first global row

    // per-lane weight fragment base: row (ct*16+m), k (ks*32+quad*8)
    const short* wb = wt + m * 128 + quad * 8;

    f32x4 acc[2][8];
    auto zacc = [&]() {
        #pragma unroll
        for (int rt = 0; rt < 2; ++rt)
            #pragma unroll
            for (int ct = 0; ct < 8; ++ct)
                #pragma unroll
                for (int r = 0; r < 4; ++r) acc[rt][ct][r] = 0.f;
    };

    // bias + SiLU + bf16 -> sAw (wave-private rows 0..31), no barrier needed
    auto epilogue = [&](const float* __restrict__ bias) {
        float bv[8];
        #pragma unroll
        for (int ct = 0; ct < 8; ++ct) bv[ct] = bias[(ct << 4) + m];
        #pragma unroll
        for (int rt = 0; rt < 2; ++rt)
            #pragma unroll
            for (int ct = 0; ct < 8; ++ct)
                #pragma unroll
                for (int r = 0; r < 4; ++r) {
                    float v = acc[rt][ct][r] + bv[ct];
                    float h = v * __builtin_amdgcn_rcpf(1.f + __expf(-v));
                    int rl = (rt << 4) + (quad << 2) + r;    // C/D: row = quad*4+reg
                    unsigned u = __builtin_bit_cast(unsigned, h) + 0x8000u;
                    sAw[swz(rl, (ct << 4) + m)] = (short)(u >> 16);
                }
    };

    // dense layer with A from the wave-private LDS slice, B from global
    auto dense = [&](int lbase) {
        zacc();
        #pragma unroll
        for (int ks = 0; ks < 4; ++ks) {
            int kk = (ks << 5) + (quad << 3);
            bf16x8 a0 = *(const bf16x8*)&sAw[swz(m, kk)];
            bf16x8 a1 = *(const bf16x8*)&sAw[swz(16 + m, kk)];
            const short* wk = wb + lbase + (ks << 5);
            #pragma unroll
            for (int ct = 0; ct < 8; ++ct) {
                bf16x8 b = *(const bf16x8*)(wk + (ct << 11));
                acc[0][ct] = __builtin_amdgcn_mfma_f32_16x16x32_bf16(a0, b, acc[0][ct], 0, 0, 0);
                acc[1][ct] = __builtin_amdgcn_mfma_f32_16x16x32_bf16(a1, b, acc[1][ct], 0, 0, 0);
            }
        }
    };

    // ---------------- layer 0: A straight from global x (packed cvt) ----
    zacc();
    {
        int g0 = grow0 + m, g1 = g0 + 16;
        long r0 = (g0 < NN) ? g0 : (NN - 1);
        long r1 = (g1 < NN) ? g1 : (NN - 1);
        const f32x4* p0 = (const f32x4*)(x + (r0 << 7)) + quad * 2;
        const f32x4* p1 = (const f32x4*)(x + (r1 << 7)) + quad * 2;
        #pragma unroll
        for (int ks = 0; ks < 4; ++ks) {
            f32x4 v0a = p0[ks * 8];
            f32x4 v0b = p0[ks * 8 + 1];
            f32x4 v1a = p1[ks * 8];
            f32x4 v1b = p1[ks * 8 + 1];
            u32x4 ua0, ua1;
            ua0[0] = pk2(v0a[0], v0a[1]); ua0[1] = pk2(v0a[2], v0a[3]);
            ua0[2] = pk2(v0b[0], v0b[1]); ua0[3] = pk2(v0b[2], v0b[3]);
            ua1[0] = pk2(v1a[0], v1a[1]); ua1[1] = pk2(v1a[2], v1a[3]);
            ua1[2] = pk2(v1b[0], v1b[1]); ua1[3] = pk2(v1b[2], v1b[3]);
            bf16x8 a0 = __builtin_bit_cast(bf16x8, ua0);
            bf16x8 a1 = __builtin_bit_cast(bf16x8, ua1);
            const short* wk = wb + (ks << 5);
            #pragma unroll
            for (int ct = 0; ct < 8; ++ct) {
                bf16x8 b = *(const bf16x8*)(wk + (ct << 11));
                acc[0][ct] = __builtin_amdgcn_mfma_f32_16x16x32_bf16(a0, b, acc[0][ct], 0, 0, 0);
                acc[1][ct] = __builtin_amdgcn_mfma_f32_16x16x32_bf16(a1, b, acc[1][ct], 0, 0, 0);
            }
        }
    }
    epilogue(b0);

    // ---------------- layers 1, 2 ----------------
    dense(16384);
    epilogue(b1);
    dense(32768);
    epilogue(b2);

    // ---------------- layer 3 + log_softmax ----------------
    f32x4 c3[2][3];
    #pragma unroll
    for (int rt = 0; rt < 2; ++rt)
        #pragma unroll
        for (int ct = 0; ct < 3; ++ct)
            #pragma unroll
            for (int r = 0; r < 4; ++r) c3[rt][ct][r] = 0.f;
    #pragma unroll
    for (int ks = 0; ks < 4; ++ks) {
        int kk = (ks << 5) + (quad << 3);
        bf16x8 a0 = *(const bf16x8*)&sAw[swz(m, kk)];
        bf16x8 a1 = *(const bf16x8*)&sAw[swz(16 + m, kk)];
        const short* wk = wb + 49152 + (ks << 5);
        #pragma unroll
        for (int ct = 0; ct < 3; ++ct) {
            bf16x8 b = *(const bf16x8*)(wk + (ct << 11));
            c3[0][ct] = __builtin_amdgcn_mfma_f32_16x16x32_bf16(a0, b, c3[0][ct], 0, 0, 0);
            c3[1][ct] = __builtin_amdgcn_mfma_f32_16x16x32_bf16(a1, b, c3[1][ct], 0, 0, 0);
        }
    }
    const bool val2 = (m < 8);                    // cols 32..39 valid
    float bv0 = b3[m];
    float bv1 = b3[16 + m];
    float bv2 = val2 ? b3[32 + m] : 0.f;
    #pragma unroll
    for (int rt = 0; rt < 2; ++rt) {
        #pragma unroll
        for (int r = 0; r < 4; ++r) {
            float v0 = c3[rt][0][r] + bv0;
            float v1 = c3[rt][1][r] + bv1;
            float v2 = c3[rt][2][r] + bv2;
            // row lives on the 16 lanes of this quad-group; reduce cols 0..39
            float mx = fmaxf(v0, v1);
            mx = val2 ? fmaxf(mx, v2) : mx;
            #pragma unroll
            for (int s = 1; s < 16; s <<= 1)
                mx = fmaxf(mx, __shfl_xor(mx, s, 64));
            float sm = __expf(v0 - mx) + __expf(v1 - mx) + (val2 ? __expf(v2 - mx) : 0.f);
            #pragma unroll
            for (int s = 1; s < 16; s <<= 1)
                sm += __shfl_xor(sm, s, 64);
            float L = mx + __logf(sm);
            int grow = grow0 + (rt << 4) + (quad << 2) + r;
            if (grow < NN) {
                float* orow = out + (long)grow * 40;
                orow[m]      = v0 - L;
                orow[16 + m] = v1 - L;
                if (val2) orow[32 + m] = v2 - L;
            }
        }
    }
}

extern "C" void kernel_launch(void* const* d_in, const int* in_sizes, int n_in,
                              void* d_out, int out_size, void* d_ws, size_t ws_size,
                              hipStream_t stream) {
    const float* x   = (const float*)d_in[0];
    // d_in[1] = edge_index (unused: ChebConv K=1 ignores the Laplacian)
    const float* W0  = (const float*)d_in[2];
    const float* bb0 = (const float*)d_in[3];
    const float* W1  = (const float*)d_in[4];
    const float* bb1 = (const float*)d_in[5];
    const float* W2  = (const float*)d_in[6];
    const float* bb2 = (const float*)d_in[7];
    const float* W3  = (const float*)d_in[8];
    const float* bb3 = (const float*)d_in[9];
    short* wt  = (short*)d_ws;         // 110592 B of bf16 transposed weights
    float* out = (float*)d_out;

    hipLaunchKernelGGL(prep_weights_k, dim3(216), dim3(256), 0, stream, W0, W1, W2, W3, wt);
    hipLaunchKernelGGL(mlp_fused_k, dim3((NN + 127) / 128), dim3(256), 0, stream,
                       x, wt, bb0, bb1, bb2, bb3, out);
}

// Round 4
// 310.944 us; speedup vs baseline: 1.0989x; 1.0694x over previous
//
#include <hip/hip_runtime.h>

#define NN 200000   // nodes; D=128 features, 40 classes (padded to 48 in wt)

typedef __attribute__((ext_vector_type(8))) short bf16x8;
typedef __attribute__((ext_vector_type(4))) float f32x4;
typedef __attribute__((ext_vector_type(4))) unsigned int u32x4;

// round-to-nearest-even fp32 -> bf16 bits (prep kernel only)
static __device__ __forceinline__ short f2bf(float f) {
    unsigned u = __builtin_bit_cast(unsigned, f);
    u += 0x7fffu + ((u >> 16) & 1u);
    return (short)(u >> 16);
}

// pack 2 floats -> 2 bf16 in one u32 (round-half-up: add 0x8000, take hi16)
static __device__ __forceinline__ unsigned pk2(float a, float b) {
    unsigned ua = __builtin_bit_cast(unsigned, a) + 0x8000u;
    unsigned ub = __builtin_bit_cast(unsigned, b) + 0x8000u;
    return __builtin_amdgcn_perm(ub, ua, 0x07060302u);
}

// XOR-swizzled LDS offset for element (r, k) of a [*,128] bf16 tile.
// 8-elem (16B) chunks xored with (r&15) -> conflict-free ds_read_b128.
static __device__ __forceinline__ int swz(int r, int k) {
    return (r << 7) + (((k >> 3) ^ (r & 15)) << 3) + (k & 7);
}

// Pre-transpose + bf16-convert weights into workspace (elements):
// [0) Wt0[n][k]=W0[k][n] 128x128 | [16384) Wt1 | [32768) Wt2 | [49152) Wt3 48x128 (n>=40 zero)
__global__ void prep_weights_k(const float* __restrict__ W0, const float* __restrict__ W1,
                               const float* __restrict__ W2, const float* __restrict__ W3,
                               short* __restrict__ wt) {
    int e = blockIdx.x * 256 + threadIdx.x;   // 216 blocks * 256 = 55296
    if (e < 49152) {
        int l = e >> 14;
        int i = e & 16383;
        int n = i >> 7, k = i & 127;
        const float* W = (l == 0) ? W0 : ((l == 1) ? W1 : W2);
        wt[e] = f2bf(W[(k << 7) + n]);
    } else if (e < 55296) {
        int i = e - 49152;
        int n = i >> 7, k = i & 127;
        wt[e] = (n < 40) ? f2bf(W3[k * 40 + n]) : (short)0;
    }
}

// Fully fused 4-layer MLP + log_softmax. ZERO __syncthreads:
//  - activations live in a per-wave-private 8KB LDS slice (32 rows x 128 bf16)
//  - weight B-fragments are loaded straight from global wt (L1/L2-hot, 108KB total)
// 32KB LDS/block; (256,3): ~100 arch VGPR + 64 AGPR acc fits WITHOUT spilling.
// ((256,4) in R2/R3 forced a 64+64 split -> scratch spills -> +65MB fetch,
//  +99MB write of scratch traffic and a 1.6x slowdown.)
__global__ __launch_bounds__(256, 3)
void mlp_fused_k(const float* __restrict__ x, const short* __restrict__ wt,
                 const float* __restrict__ b0, const float* __restrict__ b1,
                 const float* __restrict__ b2, const float* __restrict__ b3,
                 float* __restrict__ out) {
    __shared__ __align__(16) short sA[4][32 * 128];   // 32 KB total

    const int tid  = (int)threadIdx.x;
    const int lane = tid & 63;
    const int wv   = tid >> 6;       // wave 0..3
    const int m    = lane & 15;      // row (A) / col (B,C) within 16-tile
    const int quad = lane >> 4;      // 0..3
    short* sAw = &sA[wv][0];         // this wave's private activation slice
    const int grow0 = (int)blockIdx.x * 128 + wv * 32;   // first global row

    // per-lane weight fragment base: row (ct*16+m), k (ks*32+quad*8)
    const short* wb = wt + m * 128 + quad * 8;

    f32x4 acc[2][8];
    auto zacc = [&]() {
        #pragma unroll
        for (int rt = 0; rt < 2; ++rt)
            #pragma unroll
            for (int ct = 0; ct < 8; ++ct)
                #pragma unroll
                for (int r = 0; r < 4; ++r) acc[rt][ct][r] = 0.f;
    };

    // bias + SiLU + bf16 -> sAw (wave-private rows 0..31), no barrier needed
    auto epilogue = [&](const float* __restrict__ bias) {
        float bv[8];
        #pragma unroll
        for (int ct = 0; ct < 8; ++ct) bv[ct] = bias[(ct << 4) + m];
        #pragma unroll
        for (int rt = 0; rt < 2; ++rt)
            #pragma unroll
            for (int ct = 0; ct < 8; ++ct)
                #pragma unroll
                for (int r = 0; r < 4; ++r) {
                    float v = acc[rt][ct][r] + bv[ct];
                    float h = v * __builtin_amdgcn_rcpf(1.f + __expf(-v));
                    int rl = (rt << 4) + (quad << 2) + r;    // C/D: row = quad*4+reg
                    unsigned u = __builtin_bit_cast(unsigned, h) + 0x8000u;
                    sAw[swz(rl, (ct << 4) + m)] = (short)(u >> 16);
                }
    };

    // dense layer with A from the wave-private LDS slice, B from global
    auto dense = [&](int lbase) {
        zacc();
        #pragma unroll
        for (int ks = 0; ks < 4; ++ks) {
            int kk = (ks << 5) + (quad << 3);
            bf16x8 a0 = *(const bf16x8*)&sAw[swz(m, kk)];
            bf16x8 a1 = *(const bf16x8*)&sAw[swz(16 + m, kk)];
            const short* wk = wb + lbase + (ks << 5);
            #pragma unroll
            for (int ct = 0; ct < 8; ++ct) {
                bf16x8 b = *(const bf16x8*)(wk + (ct << 11));
                acc[0][ct] = __builtin_amdgcn_mfma_f32_16x16x32_bf16(a0, b, acc[0][ct], 0, 0, 0);
                acc[1][ct] = __builtin_amdgcn_mfma_f32_16x16x32_bf16(a1, b, acc[1][ct], 0, 0, 0);
            }
        }
    };

    // ---------------- layer 0: A straight from global x (packed cvt) ----
    zacc();
    {
        int g0 = grow0 + m, g1 = g0 + 16;
        long r0 = (g0 < NN) ? g0 : (NN - 1);
        long r1 = (g1 < NN) ? g1 : (NN - 1);
        const f32x4* p0 = (const f32x4*)(x + (r0 << 7)) + quad * 2;
        const f32x4* p1 = (const f32x4*)(x + (r1 << 7)) + quad * 2;
        #pragma unroll
        for (int ks = 0; ks < 4; ++ks) {
            f32x4 v0a = p0[ks * 8];
            f32x4 v0b = p0[ks * 8 + 1];
            f32x4 v1a = p1[ks * 8];
            f32x4 v1b = p1[ks * 8 + 1];
            u32x4 ua0, ua1;
            ua0[0] = pk2(v0a[0], v0a[1]); ua0[1] = pk2(v0a[2], v0a[3]);
            ua0[2] = pk2(v0b[0], v0b[1]); ua0[3] = pk2(v0b[2], v0b[3]);
            ua1[0] = pk2(v1a[0], v1a[1]); ua1[1] = pk2(v1a[2], v1a[3]);
            ua1[2] = pk2(v1b[0], v1b[1]); ua1[3] = pk2(v1b[2], v1b[3]);
            bf16x8 a0 = __builtin_bit_cast(bf16x8, ua0);
            bf16x8 a1 = __builtin_bit_cast(bf16x8, ua1);
            const short* wk = wb + (ks << 5);
            #pragma unroll
            for (int ct = 0; ct < 8; ++ct) {
                bf16x8 b = *(const bf16x8*)(wk + (ct << 11));
                acc[0][ct] = __builtin_amdgcn_mfma_f32_16x16x32_bf16(a0, b, acc[0][ct], 0, 0, 0);
                acc[1][ct] = __builtin_amdgcn_mfma_f32_16x16x32_bf16(a1, b, acc[1][ct], 0, 0, 0);
            }
        }
    }
    epilogue(b0);

    // ---------------- layers 1, 2 ----------------
    dense(16384);
    epilogue(b1);
    dense(32768);
    epilogue(b2);

    // ---------------- layer 3 + log_softmax ----------------
    f32x4 c3[2][3];
    #pragma unroll
    for (int rt = 0; rt < 2; ++rt)
        #pragma unroll
        for (int ct = 0; ct < 3; ++ct)
            #pragma unroll
            for (int r = 0; r < 4; ++r) c3[rt][ct][r] = 0.f;
    #pragma unroll
    for (int ks = 0; ks < 4; ++ks) {
        int kk = (ks << 5) + (quad << 3);
        bf16x8 a0 = *(const bf16x8*)&sAw[swz(m, kk)];
        bf16x8 a1 = *(const bf16x8*)&sAw[swz(16 + m, kk)];
        const short* wk = wb + 49152 + (ks << 5);
        #pragma unroll
        for (int ct = 0; ct < 3; ++ct) {
            bf16x8 b = *(const bf16x8*)(wk + (ct << 11));
            c3[0][ct] = __builtin_amdgcn_mfma_f32_16x16x32_bf16(a0, b, c3[0][ct], 0, 0, 0);
            c3[1][ct] = __builtin_amdgcn_mfma_f32_16x16x32_bf16(a1, b, c3[1][ct], 0, 0, 0);
        }
    }
    const bool val2 = (m < 8);                    // cols 32..39 valid
    float bv0 = b3[m];
    float bv1 = b3[16 + m];
    float bv2 = val2 ? b3[32 + m] : 0.f;
    #pragma unroll
    for (int rt = 0; rt < 2; ++rt) {
        #pragma unroll
        for (int r = 0; r < 4; ++r) {
            float v0 = c3[rt][0][r] + bv0;
            float v1 = c3[rt][1][r] + bv1;
            float v2 = c3[rt][2][r] + bv2;
            // row lives on the 16 lanes of this quad-group; reduce cols 0..39
            float mx = fmaxf(v0, v1);
            mx = val2 ? fmaxf(mx, v2) : mx;
            #pragma unroll
            for (int s = 1; s < 16; s <<= 1)
                mx = fmaxf(mx, __shfl_xor(mx, s, 64));
            float sm = __expf(v0 - mx) + __expf(v1 - mx) + (val2 ? __expf(v2 - mx) : 0.f);
            #pragma unroll
            for (int s = 1; s < 16; s <<= 1)
                sm += __shfl_xor(sm, s, 64);
            float L = mx + __logf(sm);
            int grow = grow0 + (rt << 4) + (quad << 2) + r;
            if (grow < NN) {
                float* orow = out + (long)grow * 40;
                orow[m]      = v0 - L;
                orow[16 + m] = v1 - L;
                if (val2) orow[32 + m] = v2 - L;
            }
        }
    }
}

extern "C" void kernel_launch(void* const* d_in, const int* in_sizes, int n_in,
                              void* d_out, int out_size, void* d_ws, size_t ws_size,
                              hipStream_t stream) {
    const float* x   = (const float*)d_in[0];
    // d_in[1] = edge_index (unused: ChebConv K=1 ignores the Laplacian)
    const float* W0  = (const float*)d_in[2];
    const float* bb0 = (const float*)d_in[3];
    const float* W1  = (const float*)d_in[4];
    const float* bb1 = (const float*)d_in[5];
    const float* W2  = (const float*)d_in[6];
    const float* bb2 = (const float*)d_in[7];
    const float* W3  = (const float*)d_in[8];
    const float* bb3 = (const float*)d_in[9];
    short* wt  = (short*)d_ws;         // 110592 B of bf16 transposed weights
    float* out = (float*)d_out;

    hipLaunchKernelGGL(prep_weights_k, dim3(216), dim3(256), 0, stream, W0, W1, W2, W3, wt);
    hipLaunchKernelGGL(mlp_fused_k, dim3((NN + 127) / 128), dim3(256), 0, stream,
                       x, wt, bb0, bb1, bb2, bb3, out);
}